// Round 2
// baseline (1515.461 us; speedup 1.0000x reference)
//
#include <hip/hip_runtime.h>
#include <hip/hip_bf16.h>

#define S_LEN 2048
#define HIDDEN 2048
#define NH 16
#define HD 128

typedef short short8 __attribute__((ext_vector_type(8)));
typedef float floatx4 __attribute__((ext_vector_type(4)));

__device__ __forceinline__ short f2bf(float f) {
  __hip_bfloat16 h = __float2bfloat16(f);  // RNE
  return __builtin_bit_cast(short, h);
}
__device__ __forceinline__ float bf2f(short s) {
  unsigned u = ((unsigned)(unsigned short)s) << 16;
  return __builtin_bit_cast(float, u);
}

// ---------------------------------------------------------------------------
// Generic bf16-MFMA GEMM: C[m,n] = sum_k A[m,k] * B[n,k]   (B^T layout)
// X3=1: split-precision bf16x3 (hi/lo decomposition, ~fp32-accurate dot)
// mode 0: C[z*strideC + row*ldc + col] = v
// mode 1: (PV split) col<128 -> Cmu[row*HIDDEN + (h0+z)*HD + col]
//                    else    -> Cls[row*HIDDEN + (h0+z)*HD + col-128]
// ---------------------------------------------------------------------------
#define BM 128
#define BN 128
#define BKK 32
#define LDSS 40  // 32 + 8 pad (bf16 elems) -> 80B row stride

template <int X3>
__global__ __launch_bounds__(256, 2) void gemm_bt_t(
    const float* __restrict__ Abase, int lda, unsigned long long strideA,
    const float* __restrict__ Bbase, int ldb, unsigned long long strideB,
    float* __restrict__ Cbase, int ldc, unsigned long long strideC,
    int K, int mode, float* __restrict__ Cmu, float* __restrict__ Cls, int h0) {
  __shared__ __attribute__((aligned(16))) short As[BM * LDSS];
  __shared__ __attribute__((aligned(16))) short Bs[BN * LDSS];
  __shared__ __attribute__((aligned(16))) short Asl[X3 ? BM * LDSS : 8];
  __shared__ __attribute__((aligned(16))) short Bsl[X3 ? BN * LDSS : 8];

  const int z = blockIdx.z;
  const float* A = Abase + (size_t)z * strideA;
  const float* B = Bbase + (size_t)z * strideB;
  const int m0 = blockIdx.y * BM;
  const int n0 = blockIdx.x * BN;
  const int tid = threadIdx.x;
  const int lane = tid & 63;
  const int wave = tid >> 6;
  const int wr = wave >> 1;  // 0..1
  const int wc = wave & 1;   // 0..1
  const int srow = tid >> 1;        // 0..127
  const int scol = (tid & 1) * 16;  // 0 or 16

  floatx4 acc[4][4];
#pragma unroll
  for (int i = 0; i < 4; ++i)
#pragma unroll
    for (int j = 0; j < 4; ++j) acc[i][j] = 0.0f;

  const int fr = lane & 15;
  const int koff = (lane >> 4) * 8;

  for (int k0 = 0; k0 < K; k0 += BKK) {
    const float4* pa =
        reinterpret_cast<const float4*>(A + (size_t)(m0 + srow) * lda + k0 + scol);
    const float4* pb =
        reinterpret_cast<const float4*>(B + (size_t)(n0 + srow) * ldb + k0 + scol);
    float4 av[4], bv[4];
#pragma unroll
    for (int u = 0; u < 4; ++u) { av[u] = pa[u]; bv[u] = pb[u]; }
    short a16[16], b16[16], a16l[16], b16l[16];
#pragma unroll
    for (int u = 0; u < 4; ++u) {
      const float af4[4] = {av[u].x, av[u].y, av[u].z, av[u].w};
      const float bf4[4] = {bv[u].x, bv[u].y, bv[u].z, bv[u].w};
#pragma unroll
      for (int e = 0; e < 4; ++e) {
        const short ah = f2bf(af4[e]);
        const short bh = f2bf(bf4[e]);
        a16[u * 4 + e] = ah;
        b16[u * 4 + e] = bh;
        if (X3) {
          a16l[u * 4 + e] = f2bf(af4[e] - bf2f(ah));
          b16l[u * 4 + e] = f2bf(bf4[e] - bf2f(bh));
        }
      }
    }
    *(short8*)&As[srow * LDSS + scol] = *(short8*)&a16[0];
    *(short8*)&As[srow * LDSS + scol + 8] = *(short8*)&a16[8];
    *(short8*)&Bs[srow * LDSS + scol] = *(short8*)&b16[0];
    *(short8*)&Bs[srow * LDSS + scol + 8] = *(short8*)&b16[8];
    if (X3) {
      *(short8*)&Asl[srow * LDSS + scol] = *(short8*)&a16l[0];
      *(short8*)&Asl[srow * LDSS + scol + 8] = *(short8*)&a16l[8];
      *(short8*)&Bsl[srow * LDSS + scol] = *(short8*)&b16l[0];
      *(short8*)&Bsl[srow * LDSS + scol + 8] = *(short8*)&b16l[8];
    }
    __syncthreads();

    short8 af[4], bfg[4], afl[4], bfl[4];
#pragma unroll
    for (int i = 0; i < 4; ++i) {
      af[i] = *(const short8*)&As[(wr * 64 + i * 16 + fr) * LDSS + koff];
      if (X3) afl[i] = *(const short8*)&Asl[(wr * 64 + i * 16 + fr) * LDSS + koff];
    }
#pragma unroll
    for (int j = 0; j < 4; ++j) {
      bfg[j] = *(const short8*)&Bs[(wc * 64 + j * 16 + fr) * LDSS + koff];
      if (X3) bfl[j] = *(const short8*)&Bsl[(wc * 64 + j * 16 + fr) * LDSS + koff];
    }
#pragma unroll
    for (int i = 0; i < 4; ++i)
#pragma unroll
      for (int j = 0; j < 4; ++j) {
        acc[i][j] =
            __builtin_amdgcn_mfma_f32_16x16x32_bf16(af[i], bfg[j], acc[i][j], 0, 0, 0);
        if (X3) {
          acc[i][j] = __builtin_amdgcn_mfma_f32_16x16x32_bf16(af[i], bfl[j], acc[i][j],
                                                              0, 0, 0);
          acc[i][j] = __builtin_amdgcn_mfma_f32_16x16x32_bf16(afl[i], bfg[j], acc[i][j],
                                                              0, 0, 0);
        }
      }
    __syncthreads();
  }

  // C/D layout: col = lane&15, row = (lane>>4)*4 + r   [verified m89/m91]
  const int cr = (lane >> 4) * 4;
  const int cc = lane & 15;
#pragma unroll
  for (int i = 0; i < 4; ++i)
#pragma unroll
    for (int j = 0; j < 4; ++j) {
      const int rowb = m0 + wr * 64 + i * 16 + cr;
      const int col = n0 + wc * 64 + j * 16 + cc;
#pragma unroll
      for (int r = 0; r < 4; ++r) {
        const float v = acc[i][j][r];
        if (mode == 0) {
          Cbase[(size_t)z * strideC + (size_t)(rowb + r) * ldc + col] = v;
        } else {
          const int h = h0 + z;
          float* dst = (col < HD) ? Cmu : Cls;
          dst[(size_t)(rowb + r) * HIDDEN + h * HD + (col & (HD - 1))] = v;
        }
      }
    }
}

// ---------------------------------------------------------------------------
// RoPE + expm1 centering + build QC/KC (per head: [q_rope(128) | a(128)]) + ck
// ck[h][s] = |k_rope|^2 + sum a_k^2
// ---------------------------------------------------------------------------
__global__ __launch_bounds__(128) void build_qk(
    const float* __restrict__ Yq, const float* __restrict__ Yk,
    const float* __restrict__ Yqs, const float* __restrict__ Yks,
    const float* __restrict__ cosp, const float* __restrict__ sinp,
    float* __restrict__ QC, float* __restrict__ KC, float* __restrict__ ck) {
  const int s = blockIdx.x;
  const int h = blockIdx.y;
  const int d = threadIdx.x;  // 0..127
  const size_t base = (size_t)s * HIDDEN + h * HD;
  const float c = cosp[s * HD + d];
  const float sn = sinp[s * HD + d];
  const float q = Yq[base + d];
  const float qp = Yq[base + (d ^ 64)];
  const float k = Yk[base + d];
  const float kp = Yk[base + (d ^ 64)];
  const float qrot = (d < 64) ? -qp : qp;
  const float krot = (d < 64) ? -kp : kp;
  const float qr = q * c + qrot * sn;
  const float kr = k * c + krot * sn;
  const float aq = expm1f(0.5f * Yqs[base + d]);
  const float ak = expm1f(0.5f * Yks[base + d]);
  const size_t o = ((size_t)h * S_LEN + s) * 256;
  QC[o + d] = qr;
  QC[o + 128 + d] = aq;
  KC[o + d] = kr;
  KC[o + 128 + d] = ak;

  float val = kr * kr + ak * ak;
#pragma unroll
  for (int off = 32; off > 0; off >>= 1) val += __shfl_down(val, off);
  __shared__ float red[2];
  if ((d & 63) == 0) red[d >> 6] = val;
  __syncthreads();
  if (d == 0) ck[(size_t)h * S_LEN + s] = red[0] + red[1];
}

// ---------------------------------------------------------------------------
// Build VT[h][n][s]: n<128 -> v_mu[s][h*128+n], else v_ls[s][h*128+n-128]
// ---------------------------------------------------------------------------
__global__ __launch_bounds__(256) void build_vt(const float* __restrict__ Yv,
                                                const float* __restrict__ Yvs,
                                                float* __restrict__ VT) {
  __shared__ float tile[32][33];
  const int s0 = blockIdx.x * 32;
  const int n0 = blockIdx.y * 32;  // never straddles 128
  const int h = blockIdx.z;
  const int tx = threadIdx.x;  // 0..31
  const int ty = threadIdx.y;  // 0..7
  const float* src = (n0 < HD) ? Yv : Yvs;
  const int c0 = n0 & (HD - 1);
#pragma unroll
  for (int r = ty; r < 32; r += 8)
    tile[r][tx] = src[(size_t)(s0 + r) * HIDDEN + h * HD + c0 + tx];
  __syncthreads();
#pragma unroll
  for (int r = ty; r < 32; r += 8)
    VT[((size_t)h * 256 + n0 + r) * S_LEN + s0 + tx] = tile[tx][r];
}

// ---------------------------------------------------------------------------
// Row softmax over P (in place). logit = (2*dot - ck[k]) / (|tau|+eps)
// ---------------------------------------------------------------------------
__global__ __launch_bounds__(256) void softmax_rows(float* __restrict__ P,
                                                    const float* __restrict__ ck,
                                                    const float* __restrict__ tau,
                                                    int h0) {
  const int q = blockIdx.x;
  const int g = blockIdx.y;
  const int h = h0 + g;
  float* row = P + ((size_t)g * S_LEN + q) * S_LEN;
  const float* ckh = ck + (size_t)h * S_LEN;
  const int t = threadIdx.x;
  const float inv = 1.0f / (fabsf(tau[0]) + 1e-6f);
  float v[8];
  float m = -1e30f;
#pragma unroll
  for (int j = 0; j < 8; ++j) {
    const int k = t + j * 256;
    const float l = (2.0f * row[k] - ckh[k]) * inv;
    v[j] = l;
    m = fmaxf(m, l);
  }
  __shared__ float red[4];
#pragma unroll
  for (int off = 32; off > 0; off >>= 1) m = fmaxf(m, __shfl_down(m, off));
  if ((t & 63) == 0) red[t >> 6] = m;
  __syncthreads();
  m = fmaxf(fmaxf(red[0], red[1]), fmaxf(red[2], red[3]));
  __syncthreads();
  float sum = 0.f;
#pragma unroll
  for (int j = 0; j < 8; ++j) {
    v[j] = __expf(v[j] - m);
    sum += v[j];
  }
#pragma unroll
  for (int off = 32; off > 0; off >>= 1) sum += __shfl_down(sum, off);
  if ((t & 63) == 0) red[t >> 6] = sum;
  __syncthreads();
  sum = red[0] + red[1] + red[2] + red[3];
  const float rs = 1.0f / sum;
#pragma unroll
  for (int j = 0; j < 8; ++j) row[t + j * 256] = v[j] * rs;
}

// ---------------------------------------------------------------------------
extern "C" void kernel_launch(void* const* d_in, const int* in_sizes, int n_in,
                              void* d_out, int out_size, void* d_ws, size_t ws_size,
                              hipStream_t stream) {
  (void)in_sizes; (void)n_in; (void)out_size; (void)ws_size;
  const float* Xmu = (const float*)d_in[0];
  const float* Xls = (const float*)d_in[1];
  const float* cosp = (const float*)d_in[2];
  const float* sinp = (const float*)d_in[3];
  const float* Wq_mu = (const float*)d_in[4];
  const float* Wk_mu = (const float*)d_in[5];
  const float* Wv_mu = (const float*)d_in[6];
  const float* Wo_mu = (const float*)d_in[7];
  const float* Wq_s = (const float*)d_in[8];
  const float* Wk_s = (const float*)d_in[9];
  const float* Wv_s = (const float*)d_in[10];
  const float* Wo_s = (const float*)d_in[11];
  const float* tau = (const float*)d_in[12];

  float* out_mu = (float*)d_out;
  float* out_ls = out_mu + (size_t)S_LEN * HIDDEN;

  float* ws = (float*)d_ws;
  const size_t SH = (size_t)S_LEN * HIDDEN;  // 4M
  float* Y0 = ws;
  float* Y1 = Y0 + SH;
  float* Y2 = Y1 + SH;
  float* Y3 = Y2 + SH;
  float* Y4 = Y3 + SH;
  float* Y5 = Y4 + SH;
  float* QC = Y5 + SH;
  float* KC = QC + (size_t)NH * S_LEN * 256;
  float* VT = KC + (size_t)NH * S_LEN * 256;
  float* ckb = VT + (size_t)NH * 256 * S_LEN;
  float* AOmu = ckb + (size_t)NH * S_LEN;
  float* AOls = AOmu + SH;
  float* Pbuf = ws;  // overlays dead Y0..Y3

  dim3 blk(256);
  dim3 gfull(HIDDEN / BN, S_LEN / BM, 1);

  // q_mu / k_mu projections: split-precision (feed the logit dot)
  gemm_bt_t<1><<<gfull, blk, 0, stream>>>(Xmu, HIDDEN, 0, Wq_mu, HIDDEN, 0, Y0, HIDDEN,
                                          0, HIDDEN, 0, nullptr, nullptr, 0);
  gemm_bt_t<1><<<gfull, blk, 0, stream>>>(Xmu, HIDDEN, 0, Wk_mu, HIDDEN, 0, Y1, HIDDEN,
                                          0, HIDDEN, 0, nullptr, nullptr, 0);
  // v / sigma projections: plain bf16 (error-insensitive paths)
  gemm_bt_t<0><<<gfull, blk, 0, stream>>>(Xmu, HIDDEN, 0, Wv_mu, HIDDEN, 0, Y2, HIDDEN,
                                          0, HIDDEN, 0, nullptr, nullptr, 0);
  gemm_bt_t<0><<<gfull, blk, 0, stream>>>(Xls, HIDDEN, 0, Wq_s, HIDDEN, 0, Y3, HIDDEN,
                                          0, HIDDEN, 0, nullptr, nullptr, 0);
  gemm_bt_t<0><<<gfull, blk, 0, stream>>>(Xls, HIDDEN, 0, Wk_s, HIDDEN, 0, Y4, HIDDEN,
                                          0, HIDDEN, 0, nullptr, nullptr, 0);
  gemm_bt_t<0><<<gfull, blk, 0, stream>>>(Xls, HIDDEN, 0, Wv_s, HIDDEN, 0, Y5, HIDDEN,
                                          0, HIDDEN, 0, nullptr, nullptr, 0);

  build_qk<<<dim3(S_LEN, NH), 128, 0, stream>>>(Y0, Y1, Y3, Y4, cosp, sinp, QC, KC, ckb);
  build_vt<<<dim3(S_LEN / 32, 256 / 32, NH), dim3(32, 8), 0, stream>>>(Y2, Y5, VT);

  const unsigned long long sQC = (unsigned long long)S_LEN * 256;
  const unsigned long long sP = (unsigned long long)S_LEN * S_LEN;
  const unsigned long long sVT = (unsigned long long)256 * S_LEN;
  for (int g = 0; g < 4; ++g) {
    const int h0 = g * 4;
    // logits dot: P = QC * KC^T  (K=256), split-precision
    gemm_bt_t<1><<<dim3(S_LEN / BN, S_LEN / BM, 4), blk, 0, stream>>>(
        QC + (size_t)h0 * sQC, 256, sQC, KC + (size_t)h0 * sQC, 256, sQC, Pbuf, S_LEN,
        sP, 256, 0, nullptr, nullptr, 0);
    softmax_rows<<<dim3(S_LEN, 4), blk, 0, stream>>>(Pbuf, ckb, tau, h0);
    // PV: AO = P * VT^T  (K=S), split mu/ls by col
    gemm_bt_t<0><<<dim3(256 / BN, S_LEN / BM, 4), blk, 0, stream>>>(
        Pbuf, S_LEN, sP, VT + (size_t)h0 * sVT, S_LEN, sVT, nullptr, 0, 0, S_LEN, 1,
        AOmu, AOls, h0);
  }

  gemm_bt_t<0><<<gfull, blk, 0, stream>>>(AOmu, HIDDEN, 0, Wo_mu, HIDDEN, 0, out_mu,
                                          HIDDEN, 0, HIDDEN, 0, nullptr, nullptr, 0);
  gemm_bt_t<0><<<gfull, blk, 0, stream>>>(AOls, HIDDEN, 0, Wo_s, HIDDEN, 0, out_ls,
                                          HIDDEN, 0, HIDDEN, 0, nullptr, nullptr, 0);
}

// Round 3
// 913.158 us; speedup vs baseline: 1.6596x; 1.6596x over previous
//
#include <hip/hip_runtime.h>
#include <hip/hip_bf16.h>

#define S_LEN 2048
#define HIDDEN 2048
#define NH 16
#define HD 128

typedef short short8 __attribute__((ext_vector_type(8)));
typedef short short4_t __attribute__((ext_vector_type(4)));
typedef float floatx4 __attribute__((ext_vector_type(4)));

// ---- ws layout (units of 1M = 1<<20 shorts) ------------------------------
// Overlays (time-disjoint):
//   P fp32 (16M fl = 32M sh) overlays [0,32M): Xmu/Xls/Xmu_lo/Y2..Y5/Wv  (all dead pre-attention)
//   Y2..Y5 (16M sh) overlay [12M,28M): Wq/Wk hi+lo (dead after q,k proj)
//   Y0f/Y1f fp32 (16M sh) overlay [84M,100M): Pbf (written later, per group)
#define MS(x) ((size_t)(x) * (size_t)(1u << 20))
#define O_XMU_HI MS(0)
#define O_XLS_HI MS(4)
#define O_XMU_LO MS(8)
#define O_WQ_HI MS(12)
#define O_WK_HI MS(16)
#define O_WQ_LO MS(20)
#define O_WK_LO MS(24)
#define O_WV MS(28)
#define O_WQS MS(32)
#define O_WKS MS(36)
#define O_WVS MS(40)
#define O_WO MS(44)
#define O_WOS MS(48)
#define O_Y2 MS(12)
#define O_Y3 MS(16)
#define O_Y4 MS(20)
#define O_Y5 MS(24)
#define O_QCHI MS(52)
#define O_KCHI MS(60)
#define O_QCLO MS(68)
#define O_KCLO MS(72)
#define O_VT MS(76)
#define O_PBF MS(84)
#define O_Y0F MS(84)
#define O_Y1F MS(92)
#define O_AOMU MS(100)
#define O_AOLS MS(104)
#define O_CK MS(108)

__device__ __forceinline__ short f2bf(float f) {
  __hip_bfloat16 h = __float2bfloat16(f);  // RNE
  return __builtin_bit_cast(short, h);
}
__device__ __forceinline__ float bf2f(short s) {
  unsigned u = ((unsigned)(unsigned short)s) << 16;
  return __builtin_bit_cast(float, u);
}

typedef __attribute__((address_space(1))) const unsigned int guint;
typedef __attribute__((address_space(3))) unsigned int luint;
__device__ __forceinline__ void gll16(const void* g, void* l) {
  __builtin_amdgcn_global_load_lds((guint*)g, (luint*)l, 16, 0, 0);
}

// ---------------------------------------------------------------------------
// Conversion pass: fp32 -> bf16 hi (+ lo for z in {0,1,2}). 4M elems per z.
// ---------------------------------------------------------------------------
__global__ __launch_bounds__(256) void cvt_all(
    const float* __restrict__ xmu, const float* __restrict__ xls,
    const float* __restrict__ wq, const float* __restrict__ wk,
    const float* __restrict__ wv, const float* __restrict__ wqs,
    const float* __restrict__ wks, const float* __restrict__ wvs,
    const float* __restrict__ wo, const float* __restrict__ wos,
    short* __restrict__ Sb) {
  const int z = blockIdx.z;
  const float* src;
  size_t ho;
  size_t lof = (size_t)-1;
  switch (z) {
    case 0: src = xmu; ho = O_XMU_HI; lof = O_XMU_LO; break;
    case 1: src = wq;  ho = O_WQ_HI;  lof = O_WQ_LO;  break;
    case 2: src = wk;  ho = O_WK_HI;  lof = O_WK_LO;  break;
    case 3: src = xls; ho = O_XLS_HI; break;
    case 4: src = wv;  ho = O_WV;  break;
    case 5: src = wqs; ho = O_WQS; break;
    case 6: src = wks; ho = O_WKS; break;
    case 7: src = wvs; ho = O_WVS; break;
    case 8: src = wo;  ho = O_WO;  break;
    default: src = wos; ho = O_WOS; break;
  }
  const size_t i = ((size_t)blockIdx.x * 256 + threadIdx.x) * 4;
  const float4 v = *(const float4*)(src + i);
  short4_t h, l;
  h.x = f2bf(v.x); h.y = f2bf(v.y); h.z = f2bf(v.z); h.w = f2bf(v.w);
  *(short4_t*)(Sb + ho + i) = h;
  if (lof != (size_t)-1) {
    l.x = f2bf(v.x - bf2f(h.x));
    l.y = f2bf(v.y - bf2f(h.y));
    l.z = f2bf(v.z - bf2f(h.z));
    l.w = f2bf(v.w - bf2f(h.w));
    *(short4_t*)(Sb + lof + i) = l;
  }
}

// ---------------------------------------------------------------------------
// Plain bf16 GEMM (m97-style): C[m,n] = sum_k A[m,k]*B[n,k], global_load_lds
// staging, 128x128 tile, BK=32. modes: 0 fp32 C; 2 bf16 Cb; 1 PV split bf16.
// ---------------------------------------------------------------------------
__global__ __launch_bounds__(256) void gemm_plain(
    const short* __restrict__ Ah, int lda, longlong4 aoff,
    const short* __restrict__ Bh, int ldb, long long strideB,
    int K, int mode,
    float* __restrict__ C, int ldc, long long strideC,
    short* __restrict__ Cb, long long strideCb,
    short* __restrict__ Cmu, short* __restrict__ Cls, int h0) {
  __shared__ __attribute__((aligned(16))) short As[128 * 32];
  __shared__ __attribute__((aligned(16))) short Bs[128 * 32];
  const int z = blockIdx.z;
  const long long ao = (z == 0) ? aoff.x : (z == 1) ? aoff.y : (z == 2) ? aoff.z : aoff.w;
  const short* A = Ah + ao;
  const short* B = Bh + (long long)z * strideB;
  const int m0 = blockIdx.y * 128, n0 = blockIdx.x * 128;
  const int tid = threadIdx.x, lane = tid & 63, wave = tid >> 6;
  const int wr = wave >> 1, wc = wave & 1;
  const int lr = lane >> 2;         // row within 16-row chunk
  const int lc = (lane & 3) * 8;    // col (8 bf16 = 16B)
  const int fr = lane & 15, koff = (lane >> 4) * 8;

  floatx4 acc[4][4];
#pragma unroll
  for (int i = 0; i < 4; ++i)
#pragma unroll
    for (int j = 0; j < 4; ++j) acc[i][j] = 0.0f;

  for (int k0 = 0; k0 < K; k0 += 32) {
#pragma unroll
    for (int j = 0; j < 2; ++j) {
      const int chunk = j * 4 + wave;
      gll16(A + (size_t)(m0 + chunk * 16 + lr) * lda + k0 + lc, &As[chunk * 512]);
      gll16(B + (size_t)(n0 + chunk * 16 + lr) * ldb + k0 + lc, &Bs[chunk * 512]);
    }
    __syncthreads();
    short8 af[4], bf[4];
#pragma unroll
    for (int i = 0; i < 4; ++i)
      af[i] = *(const short8*)&As[(wr * 64 + i * 16 + fr) * 32 + koff];
#pragma unroll
    for (int j = 0; j < 4; ++j)
      bf[j] = *(const short8*)&Bs[(wc * 64 + j * 16 + fr) * 32 + koff];
#pragma unroll
    for (int i = 0; i < 4; ++i)
#pragma unroll
      for (int j = 0; j < 4; ++j)
        acc[i][j] = __builtin_amdgcn_mfma_f32_16x16x32_bf16(af[i], bf[j], acc[i][j], 0, 0, 0);
    __syncthreads();
  }

  const int cr = (lane >> 4) * 4, cc = lane & 15;
#pragma unroll
  for (int i = 0; i < 4; ++i)
#pragma unroll
    for (int j = 0; j < 4; ++j) {
      const int rowb = m0 + wr * 64 + i * 16 + cr;
      const int col = n0 + wc * 64 + j * 16 + cc;
#pragma unroll
      for (int r = 0; r < 4; ++r) {
        const float v = acc[i][j][r];
        if (mode == 0) {
          C[(long long)z * strideC + (size_t)(rowb + r) * ldc + col] = v;
        } else if (mode == 2) {
          Cb[(long long)z * strideCb + (size_t)(rowb + r) * ldc + col] = f2bf(v);
        } else {
          short* dst = (col < HD) ? Cmu : Cls;
          dst[(size_t)(rowb + r) * HIDDEN + (h0 + z) * HD + (col & (HD - 1))] = f2bf(v);
        }
      }
    }
}

// ---------------------------------------------------------------------------
// Split-precision (bf16x3) GEMM: x3 for k<K3, plain beyond. fp32 C out.
// ---------------------------------------------------------------------------
__global__ __launch_bounds__(256) void gemm_x3(
    const short* __restrict__ Ah, const short* __restrict__ Al, int lda, int ldal,
    longlong4 aoff, longlong4 aoffl,
    const short* __restrict__ Bh, const short* __restrict__ Bl, int ldb, int ldbl,
    long long strideB, long long strideBl, int K, int K3,
    float* __restrict__ C, int ldc, long long strideC) {
  __shared__ __attribute__((aligned(16))) short As[128 * 32];
  __shared__ __attribute__((aligned(16))) short Bs[128 * 32];
  __shared__ __attribute__((aligned(16))) short Asl[128 * 32];
  __shared__ __attribute__((aligned(16))) short Bsl[128 * 32];
  const int z = blockIdx.z;
  const long long ao = (z == 0) ? aoff.x : (z == 1) ? aoff.y : (z == 2) ? aoff.z : aoff.w;
  const long long aol = (z == 0) ? aoffl.x : (z == 1) ? aoffl.y : (z == 2) ? aoffl.z : aoffl.w;
  const short* A = Ah + ao;
  const short* ALo = Al + aol;
  const short* B = Bh + (long long)z * strideB;
  const short* BLo = Bl + (long long)z * strideBl;
  const int m0 = blockIdx.y * 128, n0 = blockIdx.x * 128;
  const int tid = threadIdx.x, lane = tid & 63, wave = tid >> 6;
  const int wr = wave >> 1, wc = wave & 1;
  const int lr = lane >> 2;
  const int lc = (lane & 3) * 8;
  const int fr = lane & 15, koff = (lane >> 4) * 8;

  floatx4 acc[4][4];
#pragma unroll
  for (int i = 0; i < 4; ++i)
#pragma unroll
    for (int j = 0; j < 4; ++j) acc[i][j] = 0.0f;

  for (int k0 = 0; k0 < K; k0 += 32) {
    const bool hl = (k0 < K3);
#pragma unroll
    for (int j = 0; j < 2; ++j) {
      const int chunk = j * 4 + wave;
      gll16(A + (size_t)(m0 + chunk * 16 + lr) * lda + k0 + lc, &As[chunk * 512]);
      gll16(B + (size_t)(n0 + chunk * 16 + lr) * ldb + k0 + lc, &Bs[chunk * 512]);
      if (hl) {
        gll16(ALo + (size_t)(m0 + chunk * 16 + lr) * ldal + k0 + lc, &Asl[chunk * 512]);
        gll16(BLo + (size_t)(n0 + chunk * 16 + lr) * ldbl + k0 + lc, &Bsl[chunk * 512]);
      }
    }
    __syncthreads();
    short8 af[4], bf[4], afl[4], bfl[4];
#pragma unroll
    for (int i = 0; i < 4; ++i) {
      af[i] = *(const short8*)&As[(wr * 64 + i * 16 + fr) * 32 + koff];
      if (hl) afl[i] = *(const short8*)&Asl[(wr * 64 + i * 16 + fr) * 32 + koff];
    }
#pragma unroll
    for (int j = 0; j < 4; ++j) {
      bf[j] = *(const short8*)&Bs[(wc * 64 + j * 16 + fr) * 32 + koff];
      if (hl) bfl[j] = *(const short8*)&Bsl[(wc * 64 + j * 16 + fr) * 32 + koff];
    }
#pragma unroll
    for (int i = 0; i < 4; ++i)
#pragma unroll
      for (int j = 0; j < 4; ++j) {
        acc[i][j] = __builtin_amdgcn_mfma_f32_16x16x32_bf16(af[i], bf[j], acc[i][j], 0, 0, 0);
        if (hl) {
          acc[i][j] = __builtin_amdgcn_mfma_f32_16x16x32_bf16(af[i], bfl[j], acc[i][j], 0, 0, 0);
          acc[i][j] = __builtin_amdgcn_mfma_f32_16x16x32_bf16(afl[i], bf[j], acc[i][j], 0, 0, 0);
        }
      }
    __syncthreads();
  }

  const int cr = (lane >> 4) * 4, cc = lane & 15;
#pragma unroll
  for (int i = 0; i < 4; ++i)
#pragma unroll
    for (int j = 0; j < 4; ++j) {
      const int rowb = m0 + wr * 64 + i * 16 + cr;
      const int col = n0 + wc * 64 + j * 16 + cc;
#pragma unroll
      for (int r = 0; r < 4; ++r)
        C[(long long)z * strideC + (size_t)(rowb + r) * ldc + col] = acc[i][j][r];
    }
}

// ---------------------------------------------------------------------------
// RoPE + expm1 + QC/KC hi/lo build + ck
// ---------------------------------------------------------------------------
__global__ __launch_bounds__(128) void build_qk(
    const float* __restrict__ Yq, const float* __restrict__ Yk,
    const short* __restrict__ Yqs, const short* __restrict__ Yks,
    const float* __restrict__ cosp, const float* __restrict__ sinp,
    short* __restrict__ QChi, short* __restrict__ QClo,
    short* __restrict__ KChi, short* __restrict__ KClo, float* __restrict__ ck) {
  const int s = blockIdx.x;
  const int h = blockIdx.y;
  const int d = threadIdx.x;  // 0..127
  const size_t base = (size_t)s * HIDDEN + h * HD;
  const float c = cosp[s * HD + d];
  const float sn = sinp[s * HD + d];
  const float q = Yq[base + d];
  const float qp = Yq[base + (d ^ 64)];
  const float k = Yk[base + d];
  const float kp = Yk[base + (d ^ 64)];
  const float qr = q * c + ((d < 64) ? -qp : qp) * sn;
  const float kr = k * c + ((d < 64) ? -kp : kp) * sn;
  const float aq = expm1f(0.5f * bf2f(Yqs[base + d]));
  const float ak = expm1f(0.5f * bf2f(Yks[base + d]));
  const size_t o256 = ((size_t)h * S_LEN + s) * 256;
  const size_t o128 = ((size_t)h * S_LEN + s) * 128;
  const short qh = f2bf(qr), kh = f2bf(kr);
  QChi[o256 + d] = qh;
  QClo[o128 + d] = f2bf(qr - bf2f(qh));
  QChi[o256 + 128 + d] = f2bf(aq);
  KChi[o256 + d] = kh;
  KClo[o128 + d] = f2bf(kr - bf2f(kh));
  KChi[o256 + 128 + d] = f2bf(ak);

  float val = kr * kr + ak * ak;
#pragma unroll
  for (int off = 32; off > 0; off >>= 1) val += __shfl_down(val, off);
  __shared__ float red[2];
  if ((d & 63) == 0) red[d >> 6] = val;
  __syncthreads();
  if (d == 0) ck[(size_t)h * S_LEN + s] = red[0] + red[1];
}

// ---------------------------------------------------------------------------
// VT[h][n][s] (bf16): n<128 -> v_mu, else v_ls
// ---------------------------------------------------------------------------
__global__ __launch_bounds__(256) void build_vt(const short* __restrict__ Yv,
                                                const short* __restrict__ Yvs,
                                                short* __restrict__ VT) {
  __shared__ short tile[32][34];
  const int s0 = blockIdx.x * 32;
  const int n0 = blockIdx.y * 32;
  const int h = blockIdx.z;
  const int tx = threadIdx.x;
  const int ty = threadIdx.y;
  const short* src = (n0 < HD) ? Yv : Yvs;
  const int c0 = n0 & (HD - 1);
#pragma unroll
  for (int r = ty; r < 32; r += 8)
    tile[r][tx] = src[(size_t)(s0 + r) * HIDDEN + h * HD + c0 + tx];
  __syncthreads();
#pragma unroll
  for (int r = ty; r < 32; r += 8)
    VT[((size_t)h * 256 + n0 + r) * S_LEN + s0 + tx] = tile[tx][r];
}

// ---------------------------------------------------------------------------
// Row softmax: P fp32 in, Pbf bf16 out. logit = (2*dot - ck[k]) / (|tau|+eps)
// ---------------------------------------------------------------------------
__global__ __launch_bounds__(256) void softmax_rows(
    const float* __restrict__ P, short* __restrict__ Pb,
    const float* __restrict__ ck, const float* __restrict__ tau, int h0) {
  const int q = blockIdx.x;
  const int g = blockIdx.y;
  const size_t ro = ((size_t)g * S_LEN + q) * S_LEN;
  const float* row = P + ro;
  const float* ckh = ck + (size_t)(h0 + g) * S_LEN;
  const int t = threadIdx.x;
  const float inv = 1.0f / (fabsf(tau[0]) + 1e-6f);
  float v[8];
  float m = -1e30f;
#pragma unroll
  for (int j = 0; j < 8; ++j) {
    const int k = t + j * 256;
    const float l = (2.0f * row[k] - ckh[k]) * inv;
    v[j] = l;
    m = fmaxf(m, l);
  }
  __shared__ float red[4];
#pragma unroll
  for (int off = 32; off > 0; off >>= 1) m = fmaxf(m, __shfl_down(m, off));
  if ((t & 63) == 0) red[t >> 6] = m;
  __syncthreads();
  m = fmaxf(fmaxf(red[0], red[1]), fmaxf(red[2], red[3]));
  __syncthreads();
  float sum = 0.f;
#pragma unroll
  for (int j = 0; j < 8; ++j) {
    v[j] = __expf(v[j] - m);
    sum += v[j];
  }
#pragma unroll
  for (int off = 32; off > 0; off >>= 1) sum += __shfl_down(sum, off);
  if ((t & 63) == 0) red[t >> 6] = sum;
  __syncthreads();
  sum = red[0] + red[1] + red[2] + red[3];
  const float rs = 1.0f / sum;
#pragma unroll
  for (int j = 0; j < 8; ++j) Pb[ro + t + j * 256] = f2bf(v[j] * rs);
}

// ---------------------------------------------------------------------------
extern "C" void kernel_launch(void* const* d_in, const int* in_sizes, int n_in,
                              void* d_out, int out_size, void* d_ws, size_t ws_size,
                              hipStream_t stream) {
  (void)in_sizes; (void)n_in; (void)out_size; (void)ws_size;
  const float* Xmu = (const float*)d_in[0];
  const float* Xls = (const float*)d_in[1];
  const float* cosp = (const float*)d_in[2];
  const float* sinp = (const float*)d_in[3];
  const float* Wq_mu = (const float*)d_in[4];
  const float* Wk_mu = (const float*)d_in[5];
  const float* Wv_mu = (const float*)d_in[6];
  const float* Wo_mu = (const float*)d_in[7];
  const float* Wq_s = (const float*)d_in[8];
  const float* Wk_s = (const float*)d_in[9];
  const float* Wv_s = (const float*)d_in[10];
  const float* Wo_s = (const float*)d_in[11];
  const float* tau = (const float*)d_in[12];

  float* out = (float*)d_out;
  short* S = (short*)d_ws;
  const longlong4 Z4 = {0, 0, 0, 0};
  const long long M4 = (long long)MS(4);

  // 1. conversions
  cvt_all<<<dim3(4096, 1, 10), 256, 0, stream>>>(Xmu, Xls, Wq_mu, Wk_mu, Wv_mu, Wq_s,
                                                 Wk_s, Wv_s, Wo_mu, Wo_s, S);

  // 2. q,k mu projections (x3, full K): Y0f/Y1f fp32
  gemm_x3<<<dim3(16, 16, 2), 256, 0, stream>>>(
      S + O_XMU_HI, S + O_XMU_LO, HIDDEN, HIDDEN, Z4, Z4,
      S + O_WQ_HI, S + O_WQ_LO, HIDDEN, HIDDEN, M4, M4, HIDDEN, HIDDEN,
      (float*)(S + O_Y0F), HIDDEN, 4194304);

  // 3. v_mu + sigma projections (plain, z=4) -> Y2..Y5 bf16
  {
    longlong4 ao = {0, (long long)MS(4), (long long)MS(4), (long long)MS(4)};
    gemm_plain<<<dim3(16, 16, 4), 256, 0, stream>>>(
        S + O_XMU_HI, HIDDEN, ao, S + O_WV, HIDDEN, M4, HIDDEN, 2,
        nullptr, HIDDEN, 0, S + O_Y2, M4, nullptr, nullptr, 0);
  }

  // 4. build QC/KC + ck, VT
  build_qk<<<dim3(S_LEN, NH), 128, 0, stream>>>(
      (const float*)(S + O_Y0F), (const float*)(S + O_Y1F), S + O_Y3, S + O_Y4,
      cosp, sinp, S + O_QCHI, S + O_QCLO, S + O_KCHI, S + O_KCLO,
      (float*)(S + O_CK));
  build_vt<<<dim3(S_LEN / 32, 256 / 32, NH), dim3(32, 8), 0, stream>>>(
      S + O_Y2, S + O_Y5, S + O_VT);

  // 5. attention, 4 heads per group
  const long long sQC = (long long)S_LEN * 256;   // 524288
  const long long sQCl = (long long)S_LEN * 128;  // 262144
  const long long sVT = (long long)256 * S_LEN;
  const long long sP = (long long)S_LEN * S_LEN;  // 4M
  float* P = (float*)S;
  short* Pbf = S + O_PBF;
  for (int g = 0; g < 4; ++g) {
    const int h0 = g * 4;
    longlong4 ao = {0, sQC, 2 * sQC, 3 * sQC};
    longlong4 aol = {0, sQCl, 2 * sQCl, 3 * sQCl};
    gemm_x3<<<dim3(16, 16, 4), 256, 0, stream>>>(
        S + O_QCHI + (size_t)h0 * sQC, S + O_QCLO + (size_t)h0 * sQCl, 256, 128, ao, aol,
        S + O_KCHI + (size_t)h0 * sQC, S + O_KCLO + (size_t)h0 * sQCl, 256, 128,
        sQC, sQCl, 256, 128, P, S_LEN, sP);
    softmax_rows<<<dim3(S_LEN, 4), 256, 0, stream>>>(P, Pbf, (const float*)(S + O_CK),
                                                     tau, h0);
    longlong4 aop = {0, sP, 2 * sP, 3 * sP};
    gemm_plain<<<dim3(2, 16, 4), 256, 0, stream>>>(
        Pbf, S_LEN, aop, S + O_VT + (size_t)h0 * sVT, S_LEN, sVT, S_LEN, 1,
        nullptr, HIDDEN, 0, nullptr, 0, S + O_AOMU, S + O_AOLS, h0);
  }

  // 6. output projections (z=2) -> d_out fp32
  {
    longlong4 ao = {0, (long long)MS(4), 0, 0};
    gemm_plain<<<dim3(16, 16, 2), 256, 0, stream>>>(
        S + O_AOMU, HIDDEN, ao, S + O_WO, HIDDEN, M4, HIDDEN, 0,
        out, HIDDEN, 4194304, nullptr, 0, nullptr, nullptr, 0);
  }
}

// Round 4
// 847.039 us; speedup vs baseline: 1.7891x; 1.0781x over previous
//
#include <hip/hip_runtime.h>
#include <hip/hip_bf16.h>

#define S_LEN 2048
#define HIDDEN 2048
#define NH 16
#define HD 128

typedef short short8 __attribute__((ext_vector_type(8)));
typedef short short4_t __attribute__((ext_vector_type(4)));
typedef float floatx4 __attribute__((ext_vector_type(4)));

// ---- ws layout (units of 1M = 1<<20 shorts) ------------------------------
#define MS(x) ((size_t)(x) * (size_t)(1u << 20))
#define O_XMU_HI MS(0)
#define O_XLS_HI MS(4)
#define O_XMU_LO MS(8)
#define O_WQ_HI MS(12)
#define O_WK_HI MS(16)
#define O_WQ_LO MS(20)
#define O_WK_LO MS(24)
#define O_WV MS(28)
#define O_WQS MS(32)
#define O_WKS MS(36)
#define O_WVS MS(40)
#define O_WO MS(44)
#define O_WOS MS(48)
#define O_Y2 MS(12)   // overlays Wq/Wk hi+lo (dead after q,k proj)
#define O_Y3 MS(16)
#define O_Y4 MS(20)
#define O_Y5 MS(24)
#define O_QCHI MS(52)  // tiled [h][qgrp128][k8(32)][q16][8]
#define O_KCHI MS(60)
#define O_QCLO MS(68)  // tiled, K=128
#define O_KCLO MS(72)
#define O_VT MS(76)    // tiled [h][ngrp16][kv8(256)][n16][8]
#define O_Y0F MS(84)   // fp32
#define O_Y1F MS(92)   // fp32
#define O_AOMU MS(100)
#define O_AOLS MS(104)
#define O_CK MS(108)

__device__ __forceinline__ short f2bf(float f) {
  __hip_bfloat16 h = __float2bfloat16(f);  // RNE
  return __builtin_bit_cast(short, h);
}
__device__ __forceinline__ float bf2f(short s) {
  unsigned u = ((unsigned)(unsigned short)s) << 16;
  return __builtin_bit_cast(float, u);
}

typedef __attribute__((address_space(1))) const unsigned int guint;
typedef __attribute__((address_space(3))) unsigned int luint;
__device__ __forceinline__ void gll16(const void* g, void* l) {
  __builtin_amdgcn_global_load_lds((guint*)g, (luint*)l, 16, 0, 0);
}

// ---------------------------------------------------------------------------
// Conversion pass: fp32 -> bf16 hi (+ lo for z in {0,1,2}).
// ---------------------------------------------------------------------------
__global__ __launch_bounds__(256) void cvt_all(
    const float* __restrict__ xmu, const float* __restrict__ xls,
    const float* __restrict__ wq, const float* __restrict__ wk,
    const float* __restrict__ wv, const float* __restrict__ wqs,
    const float* __restrict__ wks, const float* __restrict__ wvs,
    const float* __restrict__ wo, const float* __restrict__ wos,
    short* __restrict__ Sb) {
  const int z = blockIdx.z;
  const float* src;
  size_t ho;
  size_t lof = (size_t)-1;
  switch (z) {
    case 0: src = xmu; ho = O_XMU_HI; lof = O_XMU_LO; break;
    case 1: src = wq;  ho = O_WQ_HI;  lof = O_WQ_LO;  break;
    case 2: src = wk;  ho = O_WK_HI;  lof = O_WK_LO;  break;
    case 3: src = xls; ho = O_XLS_HI; break;
    case 4: src = wv;  ho = O_WV;  break;
    case 5: src = wqs; ho = O_WQS; break;
    case 6: src = wks; ho = O_WKS; break;
    case 7: src = wvs; ho = O_WVS; break;
    case 8: src = wo;  ho = O_WO;  break;
    default: src = wos; ho = O_WOS; break;
  }
  const size_t i = ((size_t)blockIdx.x * 256 + threadIdx.x) * 4;
  const float4 v = *(const float4*)(src + i);
  short4_t h, l;
  h.x = f2bf(v.x); h.y = f2bf(v.y); h.z = f2bf(v.z); h.w = f2bf(v.w);
  *(short4_t*)(Sb + ho + i) = h;
  if (lof != (size_t)-1) {
    l.x = f2bf(v.x - bf2f(h.x));
    l.y = f2bf(v.y - bf2f(h.y));
    l.z = f2bf(v.z - bf2f(h.z));
    l.w = f2bf(v.w - bf2f(h.w));
    *(short4_t*)(Sb + lof + i) = l;
  }
}

// ---------------------------------------------------------------------------
// Plain bf16 GEMM (m97-style). modes: 0 fp32 C; 2 bf16 Cb.
// ---------------------------------------------------------------------------
__global__ __launch_bounds__(256) void gemm_plain(
    const short* __restrict__ Ah, int lda, longlong4 aoff,
    const short* __restrict__ Bh, int ldb, long long strideB,
    int K, int mode,
    float* __restrict__ C, int ldc, long long strideC,
    short* __restrict__ Cb, long long strideCb) {
  __shared__ __attribute__((aligned(16))) short As[128 * 32];
  __shared__ __attribute__((aligned(16))) short Bs[128 * 32];
  const int z = blockIdx.z;
  const long long ao = (z == 0) ? aoff.x : (z == 1) ? aoff.y : (z == 2) ? aoff.z : aoff.w;
  const short* A = Ah + ao;
  const short* B = Bh + (long long)z * strideB;
  const int m0 = blockIdx.y * 128, n0 = blockIdx.x * 128;
  const int tid = threadIdx.x, lane = tid & 63, wave = tid >> 6;
  const int wr = wave >> 1, wc = wave & 1;
  const int lr = lane >> 2;
  const int lc = (lane & 3) * 8;
  const int fr = lane & 15, koff = (lane >> 4) * 8;

  floatx4 acc[4][4];
#pragma unroll
  for (int i = 0; i < 4; ++i)
#pragma unroll
    for (int j = 0; j < 4; ++j) acc[i][j] = 0.0f;

  for (int k0 = 0; k0 < K; k0 += 32) {
#pragma unroll
    for (int j = 0; j < 2; ++j) {
      const int chunk = j * 4 + wave;
      gll16(A + (size_t)(m0 + chunk * 16 + lr) * lda + k0 + lc, &As[chunk * 512]);
      gll16(B + (size_t)(n0 + chunk * 16 + lr) * ldb + k0 + lc, &Bs[chunk * 512]);
    }
    __syncthreads();
    short8 af[4], bf[4];
#pragma unroll
    for (int i = 0; i < 4; ++i)
      af[i] = *(const short8*)&As[(wr * 64 + i * 16 + fr) * 32 + koff];
#pragma unroll
    for (int j = 0; j < 4; ++j)
      bf[j] = *(const short8*)&Bs[(wc * 64 + j * 16 + fr) * 32 + koff];
#pragma unroll
    for (int i = 0; i < 4; ++i)
#pragma unroll
      for (int j = 0; j < 4; ++j)
        acc[i][j] = __builtin_amdgcn_mfma_f32_16x16x32_bf16(af[i], bf[j], acc[i][j], 0, 0, 0);
    __syncthreads();
  }

  const int cr = (lane >> 4) * 4, cc = lane & 15;
#pragma unroll
  for (int i = 0; i < 4; ++i)
#pragma unroll
    for (int j = 0; j < 4; ++j) {
      const int rowb = m0 + wr * 64 + i * 16 + cr;
      const int col = n0 + wc * 64 + j * 16 + cc;
#pragma unroll
      for (int r = 0; r < 4; ++r) {
        const float v = acc[i][j][r];
        if (mode == 0) {
          C[(long long)z * strideC + (size_t)(rowb + r) * ldc + col] = v;
        } else {
          Cb[(long long)z * strideCb + (size_t)(rowb + r) * ldc + col] = f2bf(v);
        }
      }
    }
}

// ---------------------------------------------------------------------------
// Split-precision (bf16x3) GEMM: x3 for k<K3, plain beyond. fp32 C out.
// ---------------------------------------------------------------------------
__global__ __launch_bounds__(256) void gemm_x3(
    const short* __restrict__ Ah, const short* __restrict__ Al, int lda, int ldal,
    longlong4 aoff, longlong4 aoffl,
    const short* __restrict__ Bh, const short* __restrict__ Bl, int ldb, int ldbl,
    long long strideB, long long strideBl, int K, int K3,
    float* __restrict__ C, int ldc, long long strideC) {
  __shared__ __attribute__((aligned(16))) short As[128 * 32];
  __shared__ __attribute__((aligned(16))) short Bs[128 * 32];
  __shared__ __attribute__((aligned(16))) short Asl[128 * 32];
  __shared__ __attribute__((aligned(16))) short Bsl[128 * 32];
  const int z = blockIdx.z;
  const long long ao = (z == 0) ? aoff.x : (z == 1) ? aoff.y : (z == 2) ? aoff.z : aoff.w;
  const long long aol = (z == 0) ? aoffl.x : (z == 1) ? aoffl.y : (z == 2) ? aoffl.z : aoffl.w;
  const short* A = Ah + ao;
  const short* ALo = Al + aol;
  const short* B = Bh + (long long)z * strideB;
  const short* BLo = Bl + (long long)z * strideBl;
  const int m0 = blockIdx.y * 128, n0 = blockIdx.x * 128;
  const int tid = threadIdx.x, lane = tid & 63, wave = tid >> 6;
  const int wr = wave >> 1, wc = wave & 1;
  const int lr = lane >> 2;
  const int lc = (lane & 3) * 8;
  const int fr = lane & 15, koff = (lane >> 4) * 8;

  floatx4 acc[4][4];
#pragma unroll
  for (int i = 0; i < 4; ++i)
#pragma unroll
    for (int j = 0; j < 4; ++j) acc[i][j] = 0.0f;

  for (int k0 = 0; k0 < K; k0 += 32) {
    const bool hl = (k0 < K3);
#pragma unroll
    for (int j = 0; j < 2; ++j) {
      const int chunk = j * 4 + wave;
      gll16(A + (size_t)(m0 + chunk * 16 + lr) * lda + k0 + lc, &As[chunk * 512]);
      gll16(B + (size_t)(n0 + chunk * 16 + lr) * ldb + k0 + lc, &Bs[chunk * 512]);
      if (hl) {
        gll16(ALo + (size_t)(m0 + chunk * 16 + lr) * ldal + k0 + lc, &Asl[chunk * 512]);
        gll16(BLo + (size_t)(n0 + chunk * 16 + lr) * ldbl + k0 + lc, &Bsl[chunk * 512]);
      }
    }
    __syncthreads();
    short8 af[4], bf[4], afl[4], bfl[4];
#pragma unroll
    for (int i = 0; i < 4; ++i) {
      af[i] = *(const short8*)&As[(wr * 64 + i * 16 + fr) * 32 + koff];
      if (hl) afl[i] = *(const short8*)&Asl[(wr * 64 + i * 16 + fr) * 32 + koff];
    }
#pragma unroll
    for (int j = 0; j < 4; ++j) {
      bf[j] = *(const short8*)&Bs[(wc * 64 + j * 16 + fr) * 32 + koff];
      if (hl) bfl[j] = *(const short8*)&Bsl[(wc * 64 + j * 16 + fr) * 32 + koff];
    }
#pragma unroll
    for (int i = 0; i < 4; ++i)
#pragma unroll
      for (int j = 0; j < 4; ++j) {
        acc[i][j] = __builtin_amdgcn_mfma_f32_16x16x32_bf16(af[i], bf[j], acc[i][j], 0, 0, 0);
        if (hl) {
          acc[i][j] = __builtin_amdgcn_mfma_f32_16x16x32_bf16(af[i], bfl[j], acc[i][j], 0, 0, 0);
          acc[i][j] = __builtin_amdgcn_mfma_f32_16x16x32_bf16(afl[i], bf[j], acc[i][j], 0, 0, 0);
        }
      }
    __syncthreads();
  }

  const int cr = (lane >> 4) * 4, cc = lane & 15;
#pragma unroll
  for (int i = 0; i < 4; ++i)
#pragma unroll
    for (int j = 0; j < 4; ++j) {
      const int rowb = m0 + wr * 64 + i * 16 + cr;
      const int col = n0 + wc * 64 + j * 16 + cc;
#pragma unroll
      for (int r = 0; r < 4; ++r)
        C[(long long)z * strideC + (size_t)(rowb + r) * ldc + col] = acc[i][j][r];
    }
}

// ---------------------------------------------------------------------------
// RoPE + expm1 + QC/KC tiled hi/lo build + ck.
// Tiled layout: elem (s,k) -> grp=(h*128+(s>>4)): grp*K16 + (k>>3)*128 + (s&15)*8 + (k&7)
// ---------------------------------------------------------------------------
__global__ __launch_bounds__(128) void build_qk(
    const float* __restrict__ Yq, const float* __restrict__ Yk,
    const short* __restrict__ Yqs, const short* __restrict__ Yks,
    const float* __restrict__ cosp, const float* __restrict__ sinp,
    short* __restrict__ QChi, short* __restrict__ QClo,
    short* __restrict__ KChi, short* __restrict__ KClo, float* __restrict__ ck) {
  const int s = blockIdx.x;
  const int h = blockIdx.y;
  const int d = threadIdx.x;  // 0..127
  const size_t base = (size_t)s * HIDDEN + h * HD;
  const float c = cosp[s * HD + d];
  const float sn = sinp[s * HD + d];
  const float q = Yq[base + d];
  const float qp = Yq[base + (d ^ 64)];
  const float k = Yk[base + d];
  const float kp = Yk[base + (d ^ 64)];
  const float qr = q * c + ((d < 64) ? -qp : qp) * sn;
  const float kr = k * c + ((d < 64) ? -kp : kp) * sn;
  const float aq = expm1f(0.5f * bf2f(Yqs[base + d]));
  const float ak = expm1f(0.5f * bf2f(Yks[base + d]));
  const size_t grp = (size_t)h * 128 + (s >> 4);
  const int s16 = s & 15;
  const size_t o_hi_d = grp * 4096 + (d >> 3) * 128 + s16 * 8 + (d & 7);
  const size_t o_hi_a = grp * 4096 + ((128 + d) >> 3) * 128 + s16 * 8 + (d & 7);
  const size_t o_lo_d = grp * 2048 + (d >> 3) * 128 + s16 * 8 + (d & 7);
  const short qh = f2bf(qr), kh = f2bf(kr);
  QChi[o_hi_d] = qh;
  QClo[o_lo_d] = f2bf(qr - bf2f(qh));
  QChi[o_hi_a] = f2bf(aq);
  KChi[o_hi_d] = kh;
  KClo[o_lo_d] = f2bf(kr - bf2f(kh));
  KChi[o_hi_a] = f2bf(ak);

  float val = kr * kr + ak * ak;
#pragma unroll
  for (int off = 32; off > 0; off >>= 1) val += __shfl_down(val, off);
  __shared__ float red[2];
  if ((d & 63) == 0) red[d >> 6] = val;
  __syncthreads();
  if (d == 0) ck[(size_t)h * S_LEN + s] = red[0] + red[1];
}

// ---------------------------------------------------------------------------
// VT tiled [h][ngrp16][kv8(256)][n16][8]: n<128 -> v_mu, else v_ls
// ---------------------------------------------------------------------------
__global__ __launch_bounds__(256) void build_vt(const short* __restrict__ Yv,
                                                const short* __restrict__ Yvs,
                                                short* __restrict__ VT) {
  __shared__ short tile[32][33];
  const int s0 = blockIdx.x * 32;
  const int n0 = blockIdx.y * 32;  // never straddles 128
  const int h = blockIdx.z;
  const int tid = threadIdx.x;
  const int tx = tid & 31;
  const int ty = tid >> 5;
  const short* src = (n0 < HD) ? Yv : Yvs;
  const int c0 = n0 & (HD - 1);
#pragma unroll
  for (int r = ty; r < 32; r += 8)
    tile[r][tx] = src[(size_t)(s0 + r) * HIDDEN + h * HD + c0 + tx];
  __syncthreads();
  // 128 chunks: nl (32) x s8 (4); threads 0..127
  if (tid < 128) {
    const int nl = tid >> 2;
    const int s8 = tid & 3;
    short8 v;
#pragma unroll
    for (int e = 0; e < 8; ++e) v[e] = tile[s8 * 8 + e][nl];
    const int n = n0 + nl;
    const int kv8 = (s0 >> 3) + s8;
    const size_t off = (size_t)h * 524288 + (size_t)(n >> 4) * 32768 + (size_t)kv8 * 128 +
                       (n & 15) * 8;
    *(short8*)&VT[off] = v;
  }
}

// ---------------------------------------------------------------------------
// Fused flash attention: S = QC·KC^T (x3 on mu-half), online softmax, O += P·V
// Grid (32 qtiles, 16 heads), 256 threads. Wave w owns 16 q-rows.
// ---------------------------------------------------------------------------
__global__ __launch_bounds__(256) void fa_kernel(
    const short* __restrict__ QChi, const short* __restrict__ QClo,
    const short* __restrict__ KChi, const short* __restrict__ KClo,
    const short* __restrict__ VT, const float* __restrict__ ck,
    const float* __restrict__ tau,
    short* __restrict__ AOmu, short* __restrict__ AOls) {
  __shared__ __attribute__((aligned(16))) short kchi[8192];  // [g2][ks8][1KB-chunk]
  __shared__ __attribute__((aligned(16))) short kclo[4096];  // [g2][ks4][1KB]
  __shared__ __attribute__((aligned(16))) short vt[8192];    // [ngrp16][1KB]
  __shared__ __attribute__((aligned(16))) short patch[2048]; // 4 waves x 1KB

  const int qt = blockIdx.x;
  const int h = blockIdx.y;
  const int tid = threadIdx.x;
  const int lane = tid & 63;
  const int w = tid >> 6;
  const int qgrp = qt * 4 + w;
  const float inv = 1.0f / (fabsf(tau[0]) + 1e-6f);

  const short* QChi_h = QChi + (size_t)h * 524288;
  const short* QClo_h = QClo + (size_t)h * 262144;
  const short* KChi_h = KChi + (size_t)h * 524288;
  const short* KClo_h = KClo + (size_t)h * 262144;
  const short* VT_h = VT + (size_t)h * 524288;
  const float* ckh = ck + (size_t)h * S_LEN;

  // Q fragments in registers
  short8 qhi[8], qlo[4];
#pragma unroll
  for (int ks = 0; ks < 8; ++ks)
    qhi[ks] = *(const short8*)&QChi_h[(size_t)qgrp * 4096 + ks * 512 + lane * 8];
#pragma unroll
  for (int ks = 0; ks < 4; ++ks)
    qlo[ks] = *(const short8*)&QClo_h[(size_t)qgrp * 2048 + ks * 512 + lane * 8];

  floatx4 o[16];
#pragma unroll
  for (int nf = 0; nf < 16; ++nf) o[nf] = 0.0f;
  float m_[4], l_[4];
#pragma unroll
  for (int r = 0; r < 4; ++r) { m_[r] = -1e30f; l_[r] = 0.0f; }

  short* patchw = &patch[w * 512];

  for (int t = 0; t < 64; ++t) {
    // ---- stage K/V tiles (kv = t*32 .. +32) ----
#pragma unroll
    for (int i = 0; i < 4; ++i) {
      const int c = w * 4 + i;
      gll16(KChi_h + (size_t)(2 * t + (c >> 3)) * 4096 + (c & 7) * 512 + lane * 8,
            &kchi[c * 512]);
    }
#pragma unroll
    for (int i = 0; i < 2; ++i) {
      const int c = w * 2 + i;
      gll16(KClo_h + (size_t)(2 * t + (c >> 2)) * 2048 + (c & 3) * 512 + lane * 8,
            &kclo[c * 512]);
    }
#pragma unroll
    for (int i = 0; i < 4; ++i) {
      const int c = w * 4 + i;
      gll16(VT_h + (size_t)c * 32768 + t * 512 + lane * 8, &vt[c * 512]);
    }
    __syncthreads();

    // ---- S = Q·K^T (16q x 32kv), x3 on first 128 of K ----
    floatx4 s0 = 0.0f, s1 = 0.0f;
#pragma unroll
    for (int ks = 0; ks < 8; ++ks) {
      const short8 b0 = *(const short8*)&kchi[ks * 512 + lane * 8];
      const short8 b1 = *(const short8*)&kchi[(8 + ks) * 512 + lane * 8];
      s0 = __builtin_amdgcn_mfma_f32_16x16x32_bf16(qhi[ks], b0, s0, 0, 0, 0);
      s1 = __builtin_amdgcn_mfma_f32_16x16x32_bf16(qhi[ks], b1, s1, 0, 0, 0);
    }
#pragma unroll
    for (int ks = 0; ks < 4; ++ks) {
      const short8 bl0 = *(const short8*)&kclo[ks * 512 + lane * 8];
      const short8 bl1 = *(const short8*)&kclo[(4 + ks) * 512 + lane * 8];
      s0 = __builtin_amdgcn_mfma_f32_16x16x32_bf16(qhi[ks], bl0, s0, 0, 0, 0);
      s1 = __builtin_amdgcn_mfma_f32_16x16x32_bf16(qhi[ks], bl1, s1, 0, 0, 0);
      const short8 b0 = *(const short8*)&kchi[ks * 512 + lane * 8];
      const short8 b1 = *(const short8*)&kchi[(8 + ks) * 512 + lane * 8];
      s0 = __builtin_amdgcn_mfma_f32_16x16x32_bf16(qlo[ks], b0, s0, 0, 0, 0);
      s1 = __builtin_amdgcn_mfma_f32_16x16x32_bf16(qlo[ks], b1, s1, 0, 0, 0);
    }

    // ---- online softmax (C-layout: col=lane&15, row=(lane>>4)*4+r) ----
    const float ck0 = ckh[t * 32 + (lane & 15)];
    const float ck1 = ckh[t * 32 + 16 + (lane & 15)];
    float p0[4], p1[4], aph[4];
#pragma unroll
    for (int r = 0; r < 4; ++r) {
      const float L0 = (2.0f * s0[r] - ck0) * inv;
      const float L1 = (2.0f * s1[r] - ck1) * inv;
      float mx = fmaxf(L0, L1);
      mx = fmaxf(mx, __shfl_xor(mx, 1));
      mx = fmaxf(mx, __shfl_xor(mx, 2));
      mx = fmaxf(mx, __shfl_xor(mx, 4));
      mx = fmaxf(mx, __shfl_xor(mx, 8));
      const float mnew = fmaxf(m_[r], mx);
      const float alpha = __expf(m_[r] - mnew);
      m_[r] = mnew;
      p0[r] = __expf(L0 - mnew);
      p1[r] = __expf(L1 - mnew);
      float sum = p0[r] + p1[r];
      sum += __shfl_xor(sum, 1);
      sum += __shfl_xor(sum, 2);
      sum += __shfl_xor(sum, 4);
      sum += __shfl_xor(sum, 8);
      l_[r] = l_[r] * alpha + sum;
      aph[r] = alpha;
    }
#pragma unroll
    for (int nf = 0; nf < 16; ++nf)
#pragma unroll
      for (int r = 0; r < 4; ++r) o[nf][r] *= aph[r];

    // ---- P (C-layout) -> A-frag layout via wave-private LDS patch ----
    {
      const int row = (lane >> 4) * 4;
      const int c0i = lane & 15;
      const int c1i = 16 + (lane & 15);
#pragma unroll
      for (int r = 0; r < 4; ++r) {
        patchw[(c0i >> 3) * 128 + (row + r) * 8 + (c0i & 7)] = f2bf(p0[r]);
        patchw[(c1i >> 3) * 128 + (row + r) * 8 + (c1i & 7)] = f2bf(p1[r]);
      }
    }
    asm volatile("s_waitcnt lgkmcnt(0)\n" ::: "memory");
    const short8 pa = *(const short8*)&patchw[lane * 8];

    // ---- O += P·V (16q x 256n, K=32) ----
#pragma unroll
    for (int nf = 0; nf < 16; ++nf) {
      const short8 vf = *(const short8*)&vt[nf * 512 + lane * 8];
      o[nf] = __builtin_amdgcn_mfma_f32_16x16x32_bf16(pa, vf, o[nf], 0, 0, 0);
    }
    __syncthreads();
  }

  // ---- epilogue: normalize, write AO (linear bf16) ----
  float rs[4];
#pragma unroll
  for (int r = 0; r < 4; ++r) rs[r] = 1.0f / l_[r];
  const int qbase = qgrp * 16 + (lane >> 4) * 4;
#pragma unroll
  for (int nf = 0; nf < 16; ++nf) {
    const int n = nf * 16 + (lane & 15);
    short* dst = (n < HD) ? AOmu : AOls;
    const int col = h * HD + (n & (HD - 1));
#pragma unroll
    for (int r = 0; r < 4; ++r)
      dst[(size_t)(qbase + r) * HIDDEN + col] = f2bf(o[nf][r] * rs[r]);
  }
}

// ---------------------------------------------------------------------------
extern "C" void kernel_launch(void* const* d_in, const int* in_sizes, int n_in,
                              void* d_out, int out_size, void* d_ws, size_t ws_size,
                              hipStream_t stream) {
  (void)in_sizes; (void)n_in; (void)out_size; (void)ws_size;
  const float* Xmu = (const float*)d_in[0];
  const float* Xls = (const float*)d_in[1];
  const float* cosp = (const float*)d_in[2];
  const float* sinp = (const float*)d_in[3];
  const float* Wq_mu = (const float*)d_in[4];
  const float* Wk_mu = (const float*)d_in[5];
  const float* Wv_mu = (const float*)d_in[6];
  const float* Wo_mu = (const float*)d_in[7];
  const float* Wq_s = (const float*)d_in[8];
  const float* Wk_s = (const float*)d_in[9];
  const float* Wv_s = (const float*)d_in[10];
  const float* Wo_s = (const float*)d_in[11];
  const float* tau = (const float*)d_in[12];

  float* out = (float*)d_out;
  short* S = (short*)d_ws;
  const longlong4 Z4 = {0, 0, 0, 0};
  const long long M4 = (long long)MS(4);

  // 1. conversions
  cvt_all<<<dim3(4096, 1, 10), 256, 0, stream>>>(Xmu, Xls, Wq_mu, Wk_mu, Wv_mu, Wq_s,
                                                 Wk_s, Wv_s, Wo_mu, Wo_s, S);

  // 2. q,k mu projections (x3, full K) -> Y0f/Y1f fp32
  gemm_x3<<<dim3(16, 16, 2), 256, 0, stream>>>(
      S + O_XMU_HI, S + O_XMU_LO, HIDDEN, HIDDEN, Z4, Z4,
      S + O_WQ_HI, S + O_WQ_LO, HIDDEN, HIDDEN, M4, M4, HIDDEN, HIDDEN,
      (float*)(S + O_Y0F), HIDDEN, 4194304);

  // 3. v_mu + sigma projections (plain, z=4) -> Y2..Y5 bf16
  {
    longlong4 ao = {0, (long long)MS(4), (long long)MS(4), (long long)MS(4)};
    gemm_plain<<<dim3(16, 16, 4), 256, 0, stream>>>(
        S + O_XMU_HI, HIDDEN, ao, S + O_WV, HIDDEN, M4, HIDDEN, 2,
        nullptr, HIDDEN, 0, S + O_Y2, M4);
  }

  // 4. build tiled QC/KC + ck, tiled VT
  build_qk<<<dim3(S_LEN, NH), 128, 0, stream>>>(
      (const float*)(S + O_Y0F), (const float*)(S + O_Y1F), S + O_Y3, S + O_Y4,
      cosp, sinp, S + O_QCHI, S + O_QCLO, S + O_KCHI, S + O_KCLO,
      (float*)(S + O_CK));
  build_vt<<<dim3(S_LEN / 32, 256 / 32, NH), 256, 0, stream>>>(S + O_Y2, S + O_Y5,
                                                               S + O_VT);

  // 5. fused flash attention -> AOmu/AOls bf16
  fa_kernel<<<dim3(32, NH), 256, 0, stream>>>(
      S + O_QCHI, S + O_QCLO, S + O_KCHI, S + O_KCLO, S + O_VT,
      (const float*)(S + O_CK), tau, S + O_AOMU, S + O_AOLS);

  // 6. output projections (z=2) -> d_out fp32
  {
    longlong4 ao = {0, (long long)MS(4), 0, 0};
    gemm_plain<<<dim3(16, 16, 2), 256, 0, stream>>>(
        S + O_AOMU, HIDDEN, ao, S + O_WO, HIDDEN, M4, HIDDEN, 0,
        out, HIDDEN, 4194304, nullptr, 0);
  }
}